// Round 1
// baseline (6869.775 us; speedup 1.0000x reference)
//
#include <hip/hip_runtime.h>
#include <stdint.h>

// ---------------------------------------------------------------------------
// RNN: S=512, B=64, IN=512, HID=1024, OUT=512, keep=0.7
// Decomposition:
//   Xh   = x @ Wihx^T + b_i2h                      (parallel GEMM, bf16 out)
//   h_t  = Xh_t + h_{t-1} @ Whh^T                  (sequential, persistent kernel)
//   out  = x @ Wiox^T + h_prev @ Wioh^T + b_i2o    (parallel GEMM, bf16 out)
//   oc   = out @ Wo1^T + h_new @ Wo2^T + b_o2o     (parallel GEMM, fp32 -> d_out)
//   d_out = log_softmax(oc * mask)                 (in-place)
// ---------------------------------------------------------------------------

typedef unsigned short ushort_t;
typedef __attribute__((ext_vector_type(8))) __bf16 bf16x8;
typedef __attribute__((ext_vector_type(4))) float f32x4;

#define M_TOT 32768      // SEQ*BATCH
#define HIDD 1024
#define IND 512
#define OUTD 512

__device__ __forceinline__ ushort_t f2bf(float f) {
  union { float f; uint32_t u; } v; v.f = f;
  uint32_t r = v.u + 0x7fffu + ((v.u >> 16) & 1u);   // RNE
  return (ushort_t)(r >> 16);
}
__device__ __forceinline__ float bf2f(ushort_t b) {
  union { uint32_t u; float f; } v; v.u = ((uint32_t)b) << 16;
  return v.f;
}

// ---------------------------------------------------------------- init -----
__global__ __launch_bounds__(256) void init_kernel(uint32_t* harr0, int* flags) {
  int i = blockIdx.x * blockDim.x + threadIdx.x;
  if (i < 32768) harr0[i] = 0;        // Harr slot 0 = h_0 = 0 (65536 bf16)
  if (i < 1024) flags[i] = 0;         // cnt[512] + step_done
}

// ---------------------------------------------------------------- pack -----
// bf16-cast x and extract packed weight slices (contiguous K rows).
__global__ __launch_bounds__(256) void pack_kernel(
    const float* __restrict__ x, const float* __restrict__ W_i2h,
    const float* __restrict__ W_i2o, const float* __restrict__ W_o2o,
    ushort_t* xB, ushort_t* Wihx, ushort_t* Whh, ushort_t* Wiox,
    ushort_t* Wioh, ushort_t* Wo1, ushort_t* Wo2) {
  int64_t i = (int64_t)blockIdx.x * blockDim.x + threadIdx.x;
  const int64_t c0 = 16777216, c1 = 17301504, c2 = 18350080, c3 = 18612224,
                c4 = 19136512, c5 = 19398656, c6 = 19922944;
  if (i < c0) { xB[i] = f2bf(x[i]); return; }
  if (i < c1) { int64_t j = i - c0; int r = j >> 9,  c = j & 511;  Wihx[j] = f2bf(W_i2h[(int64_t)r * 1536 + c]); return; }
  if (i < c2) { int64_t j = i - c1; int r = j >> 10, c = j & 1023; Whh[j]  = f2bf(W_i2h[(int64_t)r * 1536 + 512 + c]); return; }
  if (i < c3) { int64_t j = i - c2; int r = j >> 9,  c = j & 511;  Wiox[j] = f2bf(W_i2o[(int64_t)r * 1536 + c]); return; }
  if (i < c4) { int64_t j = i - c3; int r = j >> 10, c = j & 1023; Wioh[j] = f2bf(W_i2o[(int64_t)r * 1536 + 512 + c]); return; }
  if (i < c5) { int64_t j = i - c4; int r = j >> 9,  c = j & 511;  Wo1[j]  = f2bf(W_o2o[(int64_t)r * 1536 + c]); return; }
  if (i < c6) { int64_t j = i - c5; int r = j >> 10, c = j & 1023; Wo2[j]  = f2bf(W_o2o[(int64_t)r * 1536 + 512 + c]); return; }
}

// ---------------------------------------------------------------- GEMM -----
// C[M,N] = A1[M,K1] @ B1[N,K1]^T + A2[M,K2] @ B2[N,K2]^T + bias[N]
// A row-major (lda), B row-major packed (ldb=K). 128x128 tile, 256 threads,
// 4 waves in 2x2 quadrants of 64x64, mfma_f32_16x16x32_bf16.
// Fragment layouts (m89/m91-verified):
//   A/B frag: lane l holds row (l&15), k = 8*(l>>4)+j  (bf16x8, contiguous k)
//   C/D:      lane l reg r -> row 4*(l>>4)+r, col l&15
__global__ __launch_bounds__(256) void gemm_bt(
    const ushort_t* __restrict__ A1, int lda1, const ushort_t* __restrict__ B1, int K1,
    const ushort_t* __restrict__ A2, int lda2, const ushort_t* __restrict__ B2, int K2,
    const float* __restrict__ bias, float* Cf, ushort_t* Cb, int Ntiles) {
  __shared__ __align__(16) ushort_t As[128][32];
  __shared__ __align__(16) ushort_t Bs[128][32];
  const int mt = blockIdx.x / Ntiles, nt = blockIdx.x % Ntiles;
  const int m0 = mt * 128, n0 = nt * 128;
  const int tid = threadIdx.x;
  const int w = tid >> 6, l = tid & 63;
  const int quad = l >> 4, l15 = l & 15;
  const int wm = (w & 1) * 64, wn = (w >> 1) * 64;
  const int r0 = tid >> 2, chunk = tid & 3;
  f32x4 acc[4][4] = {};

  for (int phase = 0; phase < 2; ++phase) {
    const ushort_t* A = phase ? A2 : A1;
    const ushort_t* B = phase ? B2 : B1;
    const int lda = phase ? lda2 : lda1;
    const int K = phase ? K2 : K1;
    for (int k0 = 0; k0 < K; k0 += 32) {
      __syncthreads();
      *(uint4*)&As[r0][chunk * 8]      = *(const uint4*)(A + (size_t)(m0 + r0) * lda + k0 + chunk * 8);
      *(uint4*)&As[r0 + 64][chunk * 8] = *(const uint4*)(A + (size_t)(m0 + r0 + 64) * lda + k0 + chunk * 8);
      *(uint4*)&Bs[r0][chunk * 8]      = *(const uint4*)(B + (size_t)(n0 + r0) * K + k0 + chunk * 8);
      *(uint4*)&Bs[r0 + 64][chunk * 8] = *(const uint4*)(B + (size_t)(n0 + r0 + 64) * K + k0 + chunk * 8);
      __syncthreads();
      bf16x8 af[4], bfr[4];
#pragma unroll
      for (int i = 0; i < 4; ++i) af[i]  = *(const bf16x8*)&As[wm + 16 * i + l15][8 * quad];
#pragma unroll
      for (int j = 0; j < 4; ++j) bfr[j] = *(const bf16x8*)&Bs[wn + 16 * j + l15][8 * quad];
#pragma unroll
      for (int i = 0; i < 4; ++i)
#pragma unroll
        for (int j = 0; j < 4; ++j)
          acc[i][j] = __builtin_amdgcn_mfma_f32_16x16x32_bf16(af[i], bfr[j], acc[i][j], 0, 0, 0);
    }
  }

  const int N = Ntiles * 128;
#pragma unroll
  for (int i = 0; i < 4; ++i) {
    const int row = m0 + wm + 16 * i + 4 * quad;
#pragma unroll
    for (int j = 0; j < 4; ++j) {
      const int col = n0 + wn + 16 * j + l15;
      const float bv = bias[col];
#pragma unroll
      for (int r = 0; r < 4; ++r) {
        const float v = acc[i][j][r] + bv;
        const size_t idx = (size_t)(row + r) * N + col;
        if (Cf) Cf[idx] = v;
        else Cb[idx] = f2bf(v);
      }
    }
  }
}

// ----------------------------------------------------------- recurrence ----
// 128 one-wave WGs: WG g -> rows [16*(g&3)..), cols [32*(g>>2)..).
// Per step: [16x32] tile of h_{t+1} = Xh_t + h_t @ Whh^T, then a centralized
// flag barrier (device-scope) so every WG can read the full h_{t+1}.
__global__ __launch_bounds__(64) void recur_kernel(
    const ushort_t* __restrict__ XhB, const ushort_t* __restrict__ Whh,
    ushort_t* Harr, int* flags) {
  const int g = blockIdx.x;
  const int rb = g & 3, cb = g >> 2;
  const int l = threadIdx.x;
  const int quad = l >> 4, l15 = l & 15;
  const int m0 = rb * 16, n0 = cb * 32;
  int* cnt = flags;                 // [512]
  int* step_done = flags + 512;

  const ushort_t* Bp0 = Whh + (size_t)(n0 + l15) * 1024 + 8 * quad;
  const ushort_t* Bp1 = Whh + (size_t)(n0 + 16 + l15) * 1024 + 8 * quad;

  for (int t = 0; t < 512; ++t) {
    const ushort_t* Ap = Harr + (size_t)t * 65536 + (size_t)(m0 + l15) * 1024 + 8 * quad;
    f32x4 acc0 = {}, acc1 = {};
#pragma unroll 4
    for (int kb = 0; kb < 32; ++kb) {
      bf16x8 a  = *(const bf16x8*)(Ap + kb * 32);
      bf16x8 b0 = *(const bf16x8*)(Bp0 + kb * 32);
      bf16x8 b1 = *(const bf16x8*)(Bp1 + kb * 32);
      acc0 = __builtin_amdgcn_mfma_f32_16x16x32_bf16(a, b0, acc0, 0, 0, 0);
      acc1 = __builtin_amdgcn_mfma_f32_16x16x32_bf16(a, b1, acc1, 0, 0, 0);
    }
    const size_t baseN = (size_t)(t + 1) * 65536;
    const size_t baseX = (size_t)t * 65536;
#pragma unroll
    for (int r = 0; r < 4; ++r) {
      const int row = m0 + 4 * quad + r;
      const size_t i0 = (size_t)row * 1024 + n0 + l15;
      const size_t i1 = i0 + 16;
      Harr[baseN + i0] = f2bf(acc0[r] + bf2f(XhB[baseX + i0]));
      Harr[baseN + i1] = f2bf(acc1[r] + bf2f(XhB[baseX + i1]));
    }
    // ---- device-scope barrier (all 128 WGs resident: 128 blocks << 256 CUs)
    __threadfence();                                    // release h stores
    if (l == 0) {
      int old = atomicAdd(&cnt[t], 1);
      if (old == 127)
        __hip_atomic_store(step_done, t + 1, __ATOMIC_RELEASE, __HIP_MEMORY_SCOPE_AGENT);
    }
    while (__hip_atomic_load(step_done, __ATOMIC_RELAXED, __HIP_MEMORY_SCOPE_AGENT) < t + 1) {}
    __threadfence();                                    // acquire before reading h_{t+1}
  }
}

// -------------------------------------------------------- mask + softmax ---
// In-place on d_out: v = oc*mask; v - max - log(sum(exp(v - max))) per row of 512.
__global__ __launch_bounds__(256) void softmax_kernel(
    float* __restrict__ out, const float* __restrict__ mask) {
  const int row = blockIdx.x;
  const int tid = threadIdx.x;
  const size_t base = (size_t)row * 512;
  __shared__ float sm[4], ss[4];
  const float v0 = out[base + tid] * mask[base + tid];
  const float v1 = out[base + tid + 256] * mask[base + tid + 256];
  float m = fmaxf(v0, v1);
#pragma unroll
  for (int off = 32; off; off >>= 1) m = fmaxf(m, __shfl_xor(m, off, 64));
  const int w = tid >> 6;
  if ((tid & 63) == 0) sm[w] = m;
  __syncthreads();
  m = fmaxf(fmaxf(sm[0], sm[1]), fmaxf(sm[2], sm[3]));
  float s = __expf(v0 - m) + __expf(v1 - m);
#pragma unroll
  for (int off = 32; off; off >>= 1) s += __shfl_xor(s, off, 64);
  if ((tid & 63) == 0) ss[w] = s;
  __syncthreads();
  s = ss[0] + ss[1] + ss[2] + ss[3];
  const float lg = logf(s);
  out[base + tid] = v0 - m - lg;
  out[base + tid + 256] = v1 - m - lg;
}

// ---------------------------------------------------------------------------
extern "C" void kernel_launch(void* const* d_in, const int* in_sizes, int n_in,
                              void* d_out, int out_size, void* d_ws, size_t ws_size,
                              hipStream_t stream) {
  const float* x     = (const float*)d_in[0];
  const float* mask  = (const float*)d_in[1];
  // W_i2h [1024,1536], b_i2h [1024], W_i2o [512,1536], b_i2o [512],
  // W_o2o [512,1536], b_o2o [512]
  const float* W_i2h = (const float*)d_in[2];
  const float* b_i2h = (const float*)d_in[3];
  const float* W_i2o = (const float*)d_in[4];
  const float* b_i2o = (const float*)d_in[5];
  const float* W_o2o = (const float*)d_in[6];
  const float* b_o2o = (const float*)d_in[7];
  float* out = (float*)d_out;

  char* ws = (char*)d_ws;
  const size_t NEED = 207753216;
  if (ws_size < NEED) return;  // fail loudly (output stays poisoned)
  ushort_t* xB   = (ushort_t*)(ws + 0);            // [32768,512] bf16
  ushort_t* XhB  = (ushort_t*)(ws + 33554432);     // [32768,1024] bf16
  ushort_t* Harr = (ushort_t*)(ws + 100663296);    // [513][64,1024] bf16
  ushort_t* OUTB = (ushort_t*)(ws + 167903232);    // [32768,512] bf16
  ushort_t* Wihx = (ushort_t*)(ws + 201457664);    // [1024,512]
  ushort_t* Whh  = (ushort_t*)(ws + 202506240);    // [1024,1024]
  ushort_t* Wiox = (ushort_t*)(ws + 204603392);    // [512,512]
  ushort_t* Wioh = (ushort_t*)(ws + 205127680);    // [512,1024]
  ushort_t* Wo1  = (ushort_t*)(ws + 206176256);    // [512,512]
  ushort_t* Wo2  = (ushort_t*)(ws + 206700544);    // [512,1024]
  int* flags     = (int*)(ws + 207749120);         // cnt[512] + step_done

  hipLaunchKernelGGL(init_kernel, dim3(128), dim3(256), 0, stream,
                     (uint32_t*)Harr, flags);
  hipLaunchKernelGGL(pack_kernel, dim3(77824), dim3(256), 0, stream,
                     x, W_i2h, W_i2o, W_o2o, xB, Wihx, Whh, Wiox, Wioh, Wo1, Wo2);
  // Xh = xB @ Wihx^T + b_i2h  (M=32768, N=1024)
  hipLaunchKernelGGL(gemm_bt, dim3(256 * 8), dim3(256), 0, stream,
                     xB, 512, Wihx, 512, (const ushort_t*)nullptr, 0,
                     (const ushort_t*)nullptr, 0, b_i2h, (float*)nullptr, XhB, 8);
  hipLaunchKernelGGL(recur_kernel, dim3(128), dim3(64), 0, stream,
                     XhB, Whh, Harr, flags);
  // out = xB @ Wiox^T + h_prev @ Wioh^T + b_i2o  (N=512)
  hipLaunchKernelGGL(gemm_bt, dim3(256 * 4), dim3(256), 0, stream,
                     xB, 512, Wiox, 512, Harr, 1024, Wioh, 1024,
                     b_i2o, (float*)nullptr, OUTB, 4);
  // oc = OUTB @ Wo1^T + h_new @ Wo2^T + b_o2o -> d_out fp32  (N=512)
  hipLaunchKernelGGL(gemm_bt, dim3(256 * 4), dim3(256), 0, stream,
                     OUTB, 512, Wo1, 512, Harr + 65536, 1024, Wo2, 1024,
                     b_o2o, out, (ushort_t*)nullptr, 4);
  hipLaunchKernelGGL(softmax_kernel, dim3(32768), dim3(256), 0, stream, out, mask);
}

// Round 2
// 1270.434 us; speedup vs baseline: 5.4074x; 5.4074x over previous
//
#include <hip/hip_runtime.h>
#include <stdint.h>
#include <string.h>

// ---------------------------------------------------------------------------
// RNN: S=512, B=64, IN=512, HID=1024, OUT=512, keep=0.7
//   Xh   = x @ Wihx^T + b_i2h                      (parallel GEMM, bf16 out)
//   h_t  = Xh_t + h_{t-1} @ Whh^T                  (CHUNKED PARALLEL SCAN)
//   out  = x @ Wiox^T + h_prev @ Wioh^T + b_i2o    (parallel GEMM, bf16 out)
//   oc   = out @ Wo1^T + h_new @ Wo2^T + b_o2o     (parallel GEMM, fp32 -> d_out)
//   d_out = log_softmax(oc * mask)                 (in-place)
//
// Scan: C=64 chunks of L=8. Pass1: zero-start partials (7 seq GEMM steps,
// M=4096 each). Combine: Hillis-Steele over chunk-start states using powers
// W^8..W^256 (8 squarings + 6 scan GEMM steps). Pass3: recompute exact h
// (8 seq GEMM steps). All plain kernel launches — no device barriers.
// ---------------------------------------------------------------------------

typedef unsigned short ushort_t;
typedef __attribute__((ext_vector_type(8))) __bf16 bf16x8;
typedef __attribute__((ext_vector_type(4))) float f32x4;

__device__ __forceinline__ ushort_t f2bf(float f) {
  union { float f; uint32_t u; } v; v.f = f;
  uint32_t r = v.u + 0x7fffu + ((v.u >> 16) & 1u);   // RNE
  return (ushort_t)(r >> 16);
}
__device__ __forceinline__ float bf2f(ushort_t b) {
  union { uint32_t u; float f; } v; v.u = ((uint32_t)b) << 16;
  return v.f;
}

// ---------------------------------------------------------------- init -----
__global__ __launch_bounds__(256) void init_kernel(uint32_t* harr0) {
  int i = blockIdx.x * blockDim.x + threadIdx.x;
  if (i < 32768) harr0[i] = 0;        // Harr slot 0 = h_0 = 0 (65536 bf16)
}

// ---------------------------------------------------------------- pack -----
__global__ __launch_bounds__(256) void pack_kernel(
    const float* __restrict__ x, const float* __restrict__ W_i2h,
    const float* __restrict__ W_i2o, const float* __restrict__ W_o2o,
    ushort_t* xB, ushort_t* Wihx, ushort_t* Whh, ushort_t* Wiox,
    ushort_t* Wioh, ushort_t* Wo1, ushort_t* Wo2) {
  int64_t i = (int64_t)blockIdx.x * blockDim.x + threadIdx.x;
  const int64_t c0 = 16777216, c1 = 17301504, c2 = 18350080, c3 = 18612224,
                c4 = 19136512, c5 = 19398656, c6 = 19922944;
  if (i < c0) { xB[i] = f2bf(x[i]); return; }
  if (i < c1) { int64_t j = i - c0; int r = j >> 9,  c = j & 511;  Wihx[j] = f2bf(W_i2h[(int64_t)r * 1536 + c]); return; }
  if (i < c2) { int64_t j = i - c1; int r = j >> 10, c = j & 1023; Whh[j]  = f2bf(W_i2h[(int64_t)r * 1536 + 512 + c]); return; }
  if (i < c3) { int64_t j = i - c2; int r = j >> 9,  c = j & 511;  Wiox[j] = f2bf(W_i2o[(int64_t)r * 1536 + c]); return; }
  if (i < c4) { int64_t j = i - c3; int r = j >> 10, c = j & 1023; Wioh[j] = f2bf(W_i2o[(int64_t)r * 1536 + 512 + c]); return; }
  if (i < c5) { int64_t j = i - c4; int r = j >> 9,  c = j & 511;  Wo1[j]  = f2bf(W_o2o[(int64_t)r * 1536 + c]); return; }
  if (i < c6) { int64_t j = i - c5; int r = j >> 10, c = j & 1023; Wo2[j]  = f2bf(W_o2o[(int64_t)r * 1536 + 512 + c]); return; }
}

// ---------------------------------------------------------------- GEMM -----
// C[M,N] = A1@B1^T + A2@B2^T + bias ; B stored [N,K] row-major. 128x128 tile.
__global__ __launch_bounds__(256) void gemm_bt(
    const ushort_t* __restrict__ A1, int lda1, const ushort_t* __restrict__ B1, int K1,
    const ushort_t* __restrict__ A2, int lda2, const ushort_t* __restrict__ B2, int K2,
    const float* __restrict__ bias, float* Cf, ushort_t* Cb, int Ntiles) {
  __shared__ __align__(16) ushort_t As[128][32];
  __shared__ __align__(16) ushort_t Bs[128][32];
  const int mt = blockIdx.x / Ntiles, nt = blockIdx.x % Ntiles;
  const int m0 = mt * 128, n0 = nt * 128;
  const int tid = threadIdx.x;
  const int w = tid >> 6, l = tid & 63;
  const int quad = l >> 4, l15 = l & 15;
  const int wm = (w & 1) * 64, wn = (w >> 1) * 64;
  const int r0 = tid >> 2, chunk = tid & 3;
  f32x4 acc[4][4] = {};

  for (int phase = 0; phase < 2; ++phase) {
    const ushort_t* A = phase ? A2 : A1;
    const ushort_t* B = phase ? B2 : B1;
    const int lda = phase ? lda2 : lda1;
    const int K = phase ? K2 : K1;
    for (int k0 = 0; k0 < K; k0 += 32) {
      __syncthreads();
      *(uint4*)&As[r0][chunk * 8]      = *(const uint4*)(A + (size_t)(m0 + r0) * lda + k0 + chunk * 8);
      *(uint4*)&As[r0 + 64][chunk * 8] = *(const uint4*)(A + (size_t)(m0 + r0 + 64) * lda + k0 + chunk * 8);
      *(uint4*)&Bs[r0][chunk * 8]      = *(const uint4*)(B + (size_t)(n0 + r0) * K + k0 + chunk * 8);
      *(uint4*)&Bs[r0 + 64][chunk * 8] = *(const uint4*)(B + (size_t)(n0 + r0 + 64) * K + k0 + chunk * 8);
      __syncthreads();
      bf16x8 af[4], bfr[4];
#pragma unroll
      for (int i = 0; i < 4; ++i) af[i]  = *(const bf16x8*)&As[wm + 16 * i + l15][8 * quad];
#pragma unroll
      for (int j = 0; j < 4; ++j) bfr[j] = *(const bf16x8*)&Bs[wn + 16 * j + l15][8 * quad];
#pragma unroll
      for (int i = 0; i < 4; ++i)
#pragma unroll
        for (int j = 0; j < 4; ++j)
          acc[i][j] = __builtin_amdgcn_mfma_f32_16x16x32_bf16(af[i], bfr[j], acc[i][j], 0, 0, 0);
    }
  }

  const int N = Ntiles * 128;
#pragma unroll
  for (int i = 0; i < 4; ++i) {
    const int row = m0 + wm + 16 * i + 4 * quad;
#pragma unroll
    for (int j = 0; j < 4; ++j) {
      const int col = n0 + wn + 16 * j + l15;
      const float bv = bias[col];
#pragma unroll
      for (int r = 0; r < 4; ++r) {
        const float v = acc[i][j][r] + bv;
        const size_t idx = (size_t)(row + r) * N + col;
        if (Cf) Cf[idx] = v;
        else Cb[idx] = f2bf(v);
      }
    }
  }
}

// ------------------------------------------------- GEMM, B non-transposed --
// O[1024,1024] = A[1024,1024] @ B[1024,1024] (plain matmul), bf16 in/out.
// Used for matrix squarings W^k -> W^2k. B tile transposed into LDS.
__global__ __launch_bounds__(256) void gemm_bn(
    const ushort_t* __restrict__ Am, const ushort_t* __restrict__ Bm,
    ushort_t* __restrict__ Om) {
  __shared__ __align__(16) ushort_t As[128][32];
  __shared__ __align__(16) ushort_t Bs[128][32];   // Bs[n][k]
  const int mt = blockIdx.x >> 3, nt = blockIdx.x & 7;
  const int m0 = mt * 128, n0 = nt * 128;
  const int tid = threadIdx.x;
  const int w = tid >> 6, l = tid & 63;
  const int quad = l >> 4, l15 = l & 15;
  const int wm = (w & 1) * 64, wn = (w >> 1) * 64;
  const int r0 = tid >> 2, chunk = tid & 3;
  f32x4 acc[4][4] = {};
  for (int k0 = 0; k0 < 1024; k0 += 32) {
    __syncthreads();
    *(uint4*)&As[r0][chunk * 8]      = *(const uint4*)(Am + (size_t)(m0 + r0) * 1024 + k0 + chunk * 8);
    *(uint4*)&As[r0 + 64][chunk * 8] = *(const uint4*)(Am + (size_t)(m0 + r0 + 64) * 1024 + k0 + chunk * 8);
#pragma unroll
    for (int rep = 0; rep < 2; ++rep) {
      const int idx = tid + 256 * rep;          // [0,512)
      const int kk = idx & 31, n8 = idx >> 5;   // kk 0..31, n8 0..15
      union { uint4 v; ushort_t s[8]; } u;
      u.v = *(const uint4*)(Bm + (size_t)(k0 + kk) * 1024 + n0 + n8 * 8);
#pragma unroll
      for (int i = 0; i < 8; ++i) Bs[n8 * 8 + i][kk] = u.s[i];
    }
    __syncthreads();
    bf16x8 af[4], bfr[4];
#pragma unroll
    for (int i = 0; i < 4; ++i) af[i]  = *(const bf16x8*)&As[wm + 16 * i + l15][8 * quad];
#pragma unroll
    for (int j = 0; j < 4; ++j) bfr[j] = *(const bf16x8*)&Bs[wn + 16 * j + l15][8 * quad];
#pragma unroll
    for (int i = 0; i < 4; ++i)
#pragma unroll
      for (int j = 0; j < 4; ++j)
        acc[i][j] = __builtin_amdgcn_mfma_f32_16x16x32_bf16(af[i], bfr[j], acc[i][j], 0, 0, 0);
  }
#pragma unroll
  for (int i = 0; i < 4; ++i) {
    const int row = m0 + wm + 16 * i + 4 * quad;
#pragma unroll
    for (int j = 0; j < 4; ++j) {
      const int col = n0 + wn + 16 * j + l15;
#pragma unroll
      for (int r = 0; r < 4; ++r)
        Om[(size_t)(row + r) * 1024 + col] = f2bf(acc[i][j][r]);
    }
  }
}

// ------------------------------------------------------------- RNN step ----
// For chunk pair (2p, 2p+1): O[c] = Xh[c] + A[c] @ Whh^T  (rows 64 per chunk).
// A chunk stride = aStride; Xh/O chunk stride fixed 524288 (= 8 slots).
__global__ __launch_bounds__(256) void rnn_step(
    const ushort_t* __restrict__ A, size_t aStride,
    const ushort_t* __restrict__ Xh, const ushort_t* __restrict__ Whh,
    ushort_t* __restrict__ O) {
  __shared__ __align__(16) ushort_t As[128][32];
  __shared__ __align__(16) ushort_t Bs[128][32];
  const int p = blockIdx.x >> 3;
  const int n0 = (blockIdx.x & 7) * 128;
  const int tid = threadIdx.x;
  const int w = tid >> 6, l = tid & 63;
  const int quad = l >> 4, l15 = l & 15;
  const int wm = (w & 1) * 64, wn = (w >> 1) * 64;
  const int r0 = tid >> 2, chunk = tid & 3;
  f32x4 acc[4][4] = {};
  const ushort_t* a0 = A + (size_t)(2 * p) * aStride + (size_t)r0 * 1024;
  const ushort_t* a1 = A + (size_t)(2 * p + 1) * aStride + (size_t)r0 * 1024;
  for (int k0 = 0; k0 < 1024; k0 += 32) {
    __syncthreads();
    *(uint4*)&As[r0][chunk * 8]      = *(const uint4*)(a0 + k0 + chunk * 8);
    *(uint4*)&As[r0 + 64][chunk * 8] = *(const uint4*)(a1 + k0 + chunk * 8);
    *(uint4*)&Bs[r0][chunk * 8]      = *(const uint4*)(Whh + (size_t)(n0 + r0) * 1024 + k0 + chunk * 8);
    *(uint4*)&Bs[r0 + 64][chunk * 8] = *(const uint4*)(Whh + (size_t)(n0 + r0 + 64) * 1024 + k0 + chunk * 8);
    __syncthreads();
    bf16x8 af[4], bfr[4];
#pragma unroll
    for (int i = 0; i < 4; ++i) af[i]  = *(const bf16x8*)&As[wm + 16 * i + l15][8 * quad];
#pragma unroll
    for (int j = 0; j < 4; ++j) bfr[j] = *(const bf16x8*)&Bs[wn + 16 * j + l15][8 * quad];
#pragma unroll
    for (int i = 0; i < 4; ++i)
#pragma unroll
      for (int j = 0; j < 4; ++j)
        acc[i][j] = __builtin_amdgcn_mfma_f32_16x16x32_bf16(af[i], bfr[j], acc[i][j], 0, 0, 0);
  }
#pragma unroll
  for (int i = 0; i < 4; ++i) {
#pragma unroll
    for (int j = 0; j < 4; ++j) {
      const int col = n0 + wn + 16 * j + l15;
#pragma unroll
      for (int r = 0; r < 4; ++r) {
        const int gr = wm + 16 * i + 4 * quad + r;        // 0..127
        const int c = 2 * p + (gr >> 6);
        const size_t idx = (size_t)c * 524288 + (size_t)(gr & 63) * 1024 + col;
        O[idx] = f2bf(acc[i][j][r] + bf2f(Xh[idx]));
      }
    }
  }
}

// ------------------------------------------------------------ scan step ----
// S_new[j] = S_old[j] + (j>=d ? S_old[j-d] @ V^T : 0), chunks 64x1024 bf16.
__global__ __launch_bounds__(256) void scan_step(
    const ushort_t* __restrict__ Sold, const ushort_t* __restrict__ V,
    ushort_t* __restrict__ Snew, int d) {
  __shared__ __align__(16) ushort_t As[128][32];
  __shared__ __align__(16) ushort_t Bs[128][32];
  const int p = blockIdx.x >> 3;
  const int n0 = (blockIdx.x & 7) * 128;
  const int tid = threadIdx.x;
  const int w = tid >> 6, l = tid & 63;
  const int quad = l >> 4, l15 = l & 15;
  const int wm = (w & 1) * 64, wn = (w >> 1) * 64;
  const int r0 = tid >> 2, chunk = tid & 3;
  f32x4 acc[4][4] = {};
  const int j0 = 2 * p, j1 = 2 * p + 1;
  const int s0 = (j0 >= d) ? j0 - d : j0;   // dummy A for invalid half
  const int s1 = (j1 >= d) ? j1 - d : j1;
  const ushort_t* a0 = Sold + (size_t)s0 * 65536 + (size_t)r0 * 1024;
  const ushort_t* a1 = Sold + (size_t)s1 * 65536 + (size_t)r0 * 1024;
  for (int k0 = 0; k0 < 1024; k0 += 32) {
    __syncthreads();
    *(uint4*)&As[r0][chunk * 8]      = *(const uint4*)(a0 + k0 + chunk * 8);
    *(uint4*)&As[r0 + 64][chunk * 8] = *(const uint4*)(a1 + k0 + chunk * 8);
    *(uint4*)&Bs[r0][chunk * 8]      = *(const uint4*)(V + (size_t)(n0 + r0) * 1024 + k0 + chunk * 8);
    *(uint4*)&Bs[r0 + 64][chunk * 8] = *(const uint4*)(V + (size_t)(n0 + r0 + 64) * 1024 + k0 + chunk * 8);
    __syncthreads();
    bf16x8 af[4], bfr[4];
#pragma unroll
    for (int i = 0; i < 4; ++i) af[i]  = *(const bf16x8*)&As[wm + 16 * i + l15][8 * quad];
#pragma unroll
    for (int j = 0; j < 4; ++j) bfr[j] = *(const bf16x8*)&Bs[wn + 16 * j + l15][8 * quad];
#pragma unroll
    for (int i = 0; i < 4; ++i)
#pragma unroll
      for (int j = 0; j < 4; ++j)
        acc[i][j] = __builtin_amdgcn_mfma_f32_16x16x32_bf16(af[i], bfr[j], acc[i][j], 0, 0, 0);
  }
#pragma unroll
  for (int i = 0; i < 4; ++i) {
#pragma unroll
    for (int j = 0; j < 4; ++j) {
      const int col = n0 + wn + 16 * j + l15;
#pragma unroll
      for (int r = 0; r < 4; ++r) {
        const int gr = wm + 16 * i + 4 * quad + r;
        const int c = 2 * p + (gr >> 6);
        const size_t idx = (size_t)c * 65536 + (size_t)(gr & 63) * 1024 + col;
        const float g = (c >= d) ? acc[i][j][r] : 0.0f;
        Snew[idx] = f2bf(g + bf2f(Sold[idx]));
      }
    }
  }
}

// ------------------------------------------------------------- copies ------
// 64 chunks of 65536 bf16 each, arbitrary chunk strides. grid 2048 x 256.
__global__ __launch_bounds__(256) void copy_strided(
    ushort_t* __restrict__ dst, size_t dStride,
    const ushort_t* __restrict__ src, size_t sStride) {
  const int c = blockIdx.x >> 5, part = blockIdx.x & 31;
  const size_t off = (size_t)part * 2048 + (size_t)threadIdx.x * 8;
  *(uint4*)(dst + (size_t)c * dStride + off) = *(const uint4*)(src + (size_t)c * sStride + off);
}

// -------------------------------------------------------- mask + softmax ---
__global__ __launch_bounds__(256) void softmax_kernel(
    float* __restrict__ out, const float* __restrict__ mask) {
  const int row = blockIdx.x;
  const int tid = threadIdx.x;
  const size_t base = (size_t)row * 512;
  __shared__ float sm[4], ss[4];
  const float v0 = out[base + tid] * mask[base + tid];
  const float v1 = out[base + tid + 256] * mask[base + tid + 256];
  float m = fmaxf(v0, v1);
#pragma unroll
  for (int off = 32; off; off >>= 1) m = fmaxf(m, __shfl_xor(m, off, 64));
  const int w = tid >> 6;
  if ((tid & 63) == 0) sm[w] = m;
  __syncthreads();
  m = fmaxf(fmaxf(sm[0], sm[1]), fmaxf(sm[2], sm[3]));
  float s = __expf(v0 - m) + __expf(v1 - m);
#pragma unroll
  for (int off = 32; off; off >>= 1) s += __shfl_xor(s, off, 64);
  if ((tid & 63) == 0) ss[w] = s;
  __syncthreads();
  s = ss[0] + ss[1] + ss[2] + ss[3];
  const float lg = logf(s);
  out[base + tid] = v0 - m - lg;
  out[base + tid + 256] = v1 - m - lg;
}

// ---------------------------------------------------------------------------
extern "C" void kernel_launch(void* const* d_in, const int* in_sizes, int n_in,
                              void* d_out, int out_size, void* d_ws, size_t ws_size,
                              hipStream_t stream) {
  const float* x     = (const float*)d_in[0];
  const float* mask  = (const float*)d_in[1];
  const float* W_i2h = (const float*)d_in[2];
  const float* b_i2h = (const float*)d_in[3];
  const float* W_i2o = (const float*)d_in[4];
  const float* b_i2o = (const float*)d_in[5];
  const float* W_o2o = (const float*)d_in[6];
  const float* b_o2o = (const float*)d_in[7];
  float* out = (float*)d_out;

  char* ws = (char*)d_ws;
  const size_t NEED = 207753216;
  if (ws_size < NEED) return;
  ushort_t* xB   = (ushort_t*)(ws + 0);            // [32768,512] bf16
  ushort_t* XhB  = (ushort_t*)(ws + 33554432);     // [512][64,1024] bf16
  ushort_t* Harr = (ushort_t*)(ws + 100663296);    // [513][64,1024] bf16
  char* outbRegion = ws + 167903232;               // 33,554,432 B (OUTB)
  ushort_t* OUTB = (ushort_t*)outbRegion;          // [32768,512] bf16 (late)
  // Scan scratch overlaid on OUTB (dead until the 'out' GEMM):
  ushort_t* SA   = (ushort_t*)(outbRegion + 0);          // [64][64,1024] bf16
  ushort_t* SB   = (ushort_t*)(outbRegion + 8388608);    // [64][64,1024] bf16
  ushort_t* P2   = (ushort_t*)(outbRegion + 0);          // temp (inside SA)
  ushort_t* P4   = (ushort_t*)(outbRegion + 2097152);    // temp (inside SA)
  ushort_t* P8   = (ushort_t*)(outbRegion + 16777216);
  ushort_t* P16  = (ushort_t*)(outbRegion + 18874368);
  ushort_t* P32  = (ushort_t*)(outbRegion + 20971520);
  ushort_t* P64  = (ushort_t*)(outbRegion + 23068672);
  ushort_t* P128 = (ushort_t*)(outbRegion + 25165824);
  ushort_t* P256 = (ushort_t*)(outbRegion + 27262976);
  ushort_t* Wihx = (ushort_t*)(ws + 201457664);
  ushort_t* Whh  = (ushort_t*)(ws + 202506240);
  ushort_t* Wiox = (ushort_t*)(ws + 204603392);
  ushort_t* Wioh = (ushort_t*)(ws + 205127680);
  ushort_t* Wo1  = (ushort_t*)(ws + 206176256);
  ushort_t* Wo2  = (ushort_t*)(ws + 206700544);

  hipLaunchKernelGGL(init_kernel, dim3(128), dim3(256), 0, stream, (uint32_t*)Harr);
  hipLaunchKernelGGL(pack_kernel, dim3(77824), dim3(256), 0, stream,
                     x, W_i2h, W_i2o, W_o2o, xB, Wihx, Whh, Wiox, Wioh, Wo1, Wo2);
  // Xh = xB @ Wihx^T + b_i2h  (M=32768, N=1024)
  hipLaunchKernelGGL(gemm_bt, dim3(256 * 8), dim3(256), 0, stream,
                     xB, 512, Wihx, 512, (const ushort_t*)nullptr, 0,
                     (const ushort_t*)nullptr, 0, b_i2h, (float*)nullptr, XhB, 8);
  // Powers W^2..W^256 (plain squarings)
  hipLaunchKernelGGL(gemm_bn, dim3(64), dim3(256), 0, stream, Whh, Whh, P2);
  hipLaunchKernelGGL(gemm_bn, dim3(64), dim3(256), 0, stream, P2, P2, P4);
  hipLaunchKernelGGL(gemm_bn, dim3(64), dim3(256), 0, stream, P4, P4, P8);
  hipLaunchKernelGGL(gemm_bn, dim3(64), dim3(256), 0, stream, P8, P8, P16);
  hipLaunchKernelGGL(gemm_bn, dim3(64), dim3(256), 0, stream, P16, P16, P32);
  hipLaunchKernelGGL(gemm_bn, dim3(64), dim3(256), 0, stream, P32, P32, P64);
  hipLaunchKernelGGL(gemm_bn, dim3(64), dim3(256), 0, stream, P64, P64, P128);
  hipLaunchKernelGGL(gemm_bn, dim3(64), dim3(256), 0, stream, P128, P128, P256);
  // Pass1 k=0: Harr[8c+1] = Xh[8c]
  hipLaunchKernelGGL(copy_strided, dim3(2048), dim3(256), 0, stream,
                     Harr + 65536, (size_t)524288, XhB, (size_t)524288);
  // Pass1 k=1..7 (zero-start partials, all 64 chunks in parallel)
  for (int k = 1; k < 8; ++k)
    hipLaunchKernelGGL(rnn_step, dim3(256), dim3(256), 0, stream,
                       Harr + (size_t)k * 65536, (size_t)524288,
                       XhB + (size_t)k * 65536, Whh, Harr + (size_t)(k + 1) * 65536);
  // Scan init: SA[c] = Harr[8c]  (c=0 slot is zeros)
  hipLaunchKernelGGL(copy_strided, dim3(2048), dim3(256), 0, stream,
                     SA, (size_t)65536, Harr, (size_t)524288);
  // Hillis-Steele over chunk-start states
  hipLaunchKernelGGL(scan_step, dim3(256), dim3(256), 0, stream, SA, P8,   SB, 1);
  hipLaunchKernelGGL(scan_step, dim3(256), dim3(256), 0, stream, SB, P16,  SA, 2);
  hipLaunchKernelGGL(scan_step, dim3(256), dim3(256), 0, stream, SA, P32,  SB, 4);
  hipLaunchKernelGGL(scan_step, dim3(256), dim3(256), 0, stream, SB, P64,  SA, 8);
  hipLaunchKernelGGL(scan_step, dim3(256), dim3(256), 0, stream, SA, P128, SB, 16);
  hipLaunchKernelGGL(scan_step, dim3(256), dim3(256), 0, stream, SB, P256, SA, 32);
  // Pass3 k=0: Harr[8c+1] = Xh[8c] + S[c] @ Whh^T
  hipLaunchKernelGGL(rnn_step, dim3(256), dim3(256), 0, stream,
                     SA, (size_t)65536, XhB, Whh, Harr + 65536);
  // Pass3 k=1..7 (exact recompute)
  for (int k = 1; k < 8; ++k)
    hipLaunchKernelGGL(rnn_step, dim3(256), dim3(256), 0, stream,
                       Harr + (size_t)k * 65536, (size_t)524288,
                       XhB + (size_t)k * 65536, Whh, Harr + (size_t)(k + 1) * 65536);
  // out = xB @ Wiox^T + h_prev @ Wioh^T + b_i2o  (N=512)
  hipLaunchKernelGGL(gemm_bt, dim3(256 * 4), dim3(256), 0, stream,
                     xB, 512, Wiox, 512, Harr, 1024, Wioh, 1024,
                     b_i2o, (float*)nullptr, OUTB, 4);
  // oc = OUTB @ Wo1^T + h_new @ Wo2^T + b_o2o -> d_out fp32  (N=512)
  hipLaunchKernelGGL(gemm_bt, dim3(256 * 4), dim3(256), 0, stream,
                     OUTB, 512, Wo1, 512, Harr + 65536, 1024, Wo2, 1024,
                     b_o2o, out, (ushort_t*)nullptr, 4);
  hipLaunchKernelGGL(softmax_kernel, dim3(32768), dim3(256), 0, stream, out, mask);
}

// Round 3
// 1253.543 us; speedup vs baseline: 5.4803x; 1.0135x over previous
//
#include <hip/hip_runtime.h>
#include <stdint.h>

// ---------------------------------------------------------------------------
// RNN: S=512, B=64, IN=512, HID=1024, OUT=512, keep=0.7
//   Xh   = x @ Wihx^T + b_i2h                      (parallel GEMM, bf16 out)
//   h_t  = Xh_t + h_{t-1} @ Whh^T                  (chunked parallel scan)
//   out  = x @ Wiox^T + h_prev @ Wioh^T + b_i2o    (parallel GEMM, bf16 out)
//   oc   = out @ Wo1^T + h_new @ Wo2^T + b_o2o     (parallel GEMM, fp32)
//   d_out = log_softmax(oc * mask)
//
// Scan: C=64 chunks of L=8. Pass1: zero-start partials (7 seq steps).
// Hillis-Steele over chunk starts (6 steps, powers W^8..W^256).
// Correction (replaces sequential pass3): ONE parallel launch doing
//   h[8c+j] = p1[8c+j] + S_c @ (W^j)^T  for j=1..8   (in-place on Harr).
// All MFMA kernels stage via global_load_lds width=16 (m97 ladder step).
// gemm_bt uses XCD-friendly tile decode (same-A blocks 256 apart -> same XCD).
// ---------------------------------------------------------------------------

typedef unsigned short ushort_t;
typedef __attribute__((ext_vector_type(8))) __bf16 bf16x8;
typedef __attribute__((ext_vector_type(4))) float f32x4;

__device__ __forceinline__ ushort_t f2bf(float f) {
  union { float f; uint32_t u; } v; v.f = f;
  uint32_t r = v.u + 0x7fffu + ((v.u >> 16) & 1u);   // RNE
  return (ushort_t)(r >> 16);
}
__device__ __forceinline__ float bf2f(ushort_t b) {
  union { uint32_t u; float f; } v; v.u = ((uint32_t)b) << 16;
  return v.f;
}

// async global->LDS, 16 bytes/lane. LDS dest contract: wave-uniform base +
// lane*16 — our staging layout is exactly &lds[tid*8] (8 bf16 = 16 B).
__device__ __forceinline__ void gload16(const ushort_t* g, ushort_t* l) {
  __builtin_amdgcn_global_load_lds(
      (const __attribute__((address_space(1))) uint32_t*)g,
      (__attribute__((address_space(3))) uint32_t*)l, 16, 0, 0);
}

// ---------------------------------------------------------------- init -----
__global__ __launch_bounds__(256) void init_kernel(uint32_t* harr0) {
  int i = blockIdx.x * blockDim.x + threadIdx.x;
  if (i < 32768) harr0[i] = 0;        // Harr slot 0 = h_0 = 0
}

// ---------------------------------------------------------------- pack -----
__global__ __launch_bounds__(256) void pack_kernel(
    const float* __restrict__ x, const float* __restrict__ W_i2h,
    const float* __restrict__ W_i2o, const float* __restrict__ W_o2o,
    ushort_t* xB, ushort_t* Wihx, ushort_t* Whh, ushort_t* Wiox,
    ushort_t* Wioh, ushort_t* Wo1, ushort_t* Wo2) {
  int64_t i = (int64_t)blockIdx.x * blockDim.x + threadIdx.x;
  const int64_t c0 = 16777216, c1 = 17301504, c2 = 18350080, c3 = 18612224,
                c4 = 19136512, c5 = 19398656, c6 = 19922944;
  if (i < c0) { xB[i] = f2bf(x[i]); return; }
  if (i < c1) { int64_t j = i - c0; int r = j >> 9,  c = j & 511;  Wihx[j] = f2bf(W_i2h[(int64_t)r * 1536 + c]); return; }
  if (i < c2) { int64_t j = i - c1; int r = j >> 10, c = j & 1023; Whh[j]  = f2bf(W_i2h[(int64_t)r * 1536 + 512 + c]); return; }
  if (i < c3) { int64_t j = i - c2; int r = j >> 9,  c = j & 511;  Wiox[j] = f2bf(W_i2o[(int64_t)r * 1536 + c]); return; }
  if (i < c4) { int64_t j = i - c3; int r = j >> 10, c = j & 1023; Wioh[j] = f2bf(W_i2o[(int64_t)r * 1536 + 512 + c]); return; }
  if (i < c5) { int64_t j = i - c4; int r = j >> 9,  c = j & 511;  Wo1[j]  = f2bf(W_o2o[(int64_t)r * 1536 + c]); return; }
  if (i < c6) { int64_t j = i - c5; int r = j >> 10, c = j & 1023; Wo2[j]  = f2bf(W_o2o[(int64_t)r * 1536 + 512 + c]); return; }
}

// ---------------------------------------------------------------- GEMM -----
// C[M,N] = A1@B1^T + A2@B2^T + bias ; B stored [N,K] row-major. 128x128 tile.
// Mtiles is always 256 (M=32768). Tile decode mt = bid&255 puts the Ntiles
// blocks sharing one A-tile 256 apart in dispatch order -> same XCD L2.
__global__ __launch_bounds__(256) void gemm_bt(
    const ushort_t* __restrict__ A1, int lda1, const ushort_t* __restrict__ B1, int K1,
    const ushort_t* __restrict__ A2, int lda2, const ushort_t* __restrict__ B2, int K2,
    const float* __restrict__ bias, float* Cf, ushort_t* Cb, int Ntiles) {
  __shared__ __align__(16) ushort_t AsF[4096];
  __shared__ __align__(16) ushort_t BsF[4096];
  const int mt = blockIdx.x & 255, nt = blockIdx.x >> 8;
  const int m0 = mt * 128, n0 = nt * 128;
  const int tid = threadIdx.x;
  const int w = tid >> 6, l = tid & 63;
  const int quad = l >> 4, l15 = l & 15;
  const int wm = (w & 1) * 64, wn = (w >> 1) * 64;
  const int r0 = tid >> 2, chunk = tid & 3;
  f32x4 acc[4][4] = {};

  for (int phase = 0; phase < 2; ++phase) {
    const ushort_t* A = phase ? A2 : A1;
    const ushort_t* B = phase ? B2 : B1;
    const int lda = phase ? lda2 : lda1;
    const int K = phase ? K2 : K1;
    for (int k0 = 0; k0 < K; k0 += 32) {
      __syncthreads();
      gload16(A + (size_t)(m0 + r0) * lda + k0 + chunk * 8,      &AsF[tid * 8]);
      gload16(A + (size_t)(m0 + r0 + 64) * lda + k0 + chunk * 8, &AsF[2048 + tid * 8]);
      gload16(B + (size_t)(n0 + r0) * K + k0 + chunk * 8,        &BsF[tid * 8]);
      gload16(B + (size_t)(n0 + r0 + 64) * K + k0 + chunk * 8,   &BsF[2048 + tid * 8]);
      __syncthreads();
      bf16x8 af[4], bfr[4];
#pragma unroll
      for (int i = 0; i < 4; ++i) af[i]  = *(const bf16x8*)&AsF[(wm + 16 * i + l15) * 32 + 8 * quad];
#pragma unroll
      for (int j = 0; j < 4; ++j) bfr[j] = *(const bf16x8*)&BsF[(wn + 16 * j + l15) * 32 + 8 * quad];
#pragma unroll
      for (int i = 0; i < 4; ++i)
#pragma unroll
        for (int j = 0; j < 4; ++j)
          acc[i][j] = __builtin_amdgcn_mfma_f32_16x16x32_bf16(af[i], bfr[j], acc[i][j], 0, 0, 0);
    }
  }

  const int N = Ntiles * 128;
#pragma unroll
  for (int i = 0; i < 4; ++i) {
    const int row = m0 + wm + 16 * i + 4 * quad;
#pragma unroll
    for (int j = 0; j < 4; ++j) {
      const int col = n0 + wn + 16 * j + l15;
      const float bv = bias[col];
#pragma unroll
      for (int r = 0; r < 4; ++r) {
        const float v = acc[i][j][r] + bv;
        const size_t idx = (size_t)(row + r) * N + col;
        if (Cf) Cf[idx] = v;
        else Cb[idx] = f2bf(v);
      }
    }
  }
}

// ------------------------------------------------- GEMM, B non-transposed --
// O[1024,1024] = A @ B (plain), bf16. For W^k squarings/products.
__global__ __launch_bounds__(256) void gemm_bn(
    const ushort_t* __restrict__ Am, const ushort_t* __restrict__ Bm,
    ushort_t* __restrict__ Om) {
  __shared__ __align__(16) ushort_t AsF[4096];
  __shared__ __align__(16) ushort_t BsF[4096];   // [n][k]
  const int mt = blockIdx.x >> 3, nt = blockIdx.x & 7;
  const int m0 = mt * 128, n0 = nt * 128;
  const int tid = threadIdx.x;
  const int w = tid >> 6, l = tid & 63;
  const int quad = l >> 4, l15 = l & 15;
  const int wm = (w & 1) * 64, wn = (w >> 1) * 64;
  const int r0 = tid >> 2, chunk = tid & 3;
  f32x4 acc[4][4] = {};
  for (int k0 = 0; k0 < 1024; k0 += 32) {
    __syncthreads();
    gload16(Am + (size_t)(m0 + r0) * 1024 + k0 + chunk * 8,      &AsF[tid * 8]);
    gload16(Am + (size_t)(m0 + r0 + 64) * 1024 + k0 + chunk * 8, &AsF[2048 + tid * 8]);
#pragma unroll
    for (int rep = 0; rep < 2; ++rep) {
      const int idx = tid + 256 * rep;          // [0,512)
      const int kk = idx & 31, n8 = idx >> 5;
      union { uint4 v; ushort_t s[8]; } u;
      u.v = *(const uint4*)(Bm + (size_t)(k0 + kk) * 1024 + n0 + n8 * 8);
#pragma unroll
      for (int i = 0; i < 8; ++i) BsF[(n8 * 8 + i) * 32 + kk] = u.s[i];
    }
    __syncthreads();
    bf16x8 af[4], bfr[4];
#pragma unroll
    for (int i = 0; i < 4; ++i) af[i]  = *(const bf16x8*)&AsF[(wm + 16 * i + l15) * 32 + 8 * quad];
#pragma unroll
    for (int j = 0; j < 4; ++j) bfr[j] = *(const bf16x8*)&BsF[(wn + 16 * j + l15) * 32 + 8 * quad];
#pragma unroll
    for (int i = 0; i < 4; ++i)
#pragma unroll
      for (int j = 0; j < 4; ++j)
        acc[i][j] = __builtin_amdgcn_mfma_f32_16x16x32_bf16(af[i], bfr[j], acc[i][j], 0, 0, 0);
  }
#pragma unroll
  for (int i = 0; i < 4; ++i) {
    const int row = m0 + wm + 16 * i + 4 * quad;
#pragma unroll
    for (int j = 0; j < 4; ++j) {
      const int col = n0 + wn + 16 * j + l15;
#pragma unroll
      for (int r = 0; r < 4; ++r)
        Om[(size_t)(row + r) * 1024 + col] = f2bf(acc[i][j][r]);
    }
  }
}

// ------------------------------------------------------------- RNN step ----
// For chunk pair (2p, 2p+1): O[c] = Xh[c] + A[c] @ Whh^T.
__global__ __launch_bounds__(256) void rnn_step(
    const ushort_t* __restrict__ A, size_t aStride,
    const ushort_t* __restrict__ Xh, const ushort_t* __restrict__ Whh,
    ushort_t* __restrict__ O) {
  __shared__ __align__(16) ushort_t AsF[4096];
  __shared__ __align__(16) ushort_t BsF[4096];
  const int p = blockIdx.x >> 3;
  const int n0 = (blockIdx.x & 7) * 128;
  const int tid = threadIdx.x;
  const int w = tid >> 6, l = tid & 63;
  const int quad = l >> 4, l15 = l & 15;
  const int wm = (w & 1) * 64, wn = (w >> 1) * 64;
  const int r0 = tid >> 2, chunk = tid & 3;
  f32x4 acc[4][4] = {};
  const ushort_t* a0 = A + (size_t)(2 * p) * aStride + (size_t)r0 * 1024;
  const ushort_t* a1 = A + (size_t)(2 * p + 1) * aStride + (size_t)r0 * 1024;
  for (int k0 = 0; k0 < 1024; k0 += 32) {
    __syncthreads();
    gload16(a0 + k0 + chunk * 8, &AsF[tid * 8]);
    gload16(a1 + k0 + chunk * 8, &AsF[2048 + tid * 8]);
    gload16(Whh + (size_t)(n0 + r0) * 1024 + k0 + chunk * 8,      &BsF[tid * 8]);
    gload16(Whh + (size_t)(n0 + r0 + 64) * 1024 + k0 + chunk * 8, &BsF[2048 + tid * 8]);
    __syncthreads();
    bf16x8 af[4], bfr[4];
#pragma unroll
    for (int i = 0; i < 4; ++i) af[i]  = *(const bf16x8*)&AsF[(wm + 16 * i + l15) * 32 + 8 * quad];
#pragma unroll
    for (int j = 0; j < 4; ++j) bfr[j] = *(const bf16x8*)&BsF[(wn + 16 * j + l15) * 32 + 8 * quad];
#pragma unroll
    for (int i = 0; i < 4; ++i)
#pragma unroll
      for (int j = 0; j < 4; ++j)
        acc[i][j] = __builtin_amdgcn_mfma_f32_16x16x32_bf16(af[i], bfr[j], acc[i][j], 0, 0, 0);
  }
#pragma unroll
  for (int i = 0; i < 4; ++i) {
#pragma unroll
    for (int j = 0; j < 4; ++j) {
      const int col = n0 + wn + 16 * j + l15;
#pragma unroll
      for (int r = 0; r < 4; ++r) {
        const int gr = wm + 16 * i + 4 * quad + r;
        const int c = 2 * p + (gr >> 6);
        const size_t idx = (size_t)c * 524288 + (size_t)(gr & 63) * 1024 + col;
        O[idx] = f2bf(acc[i][j][r] + bf2f(Xh[idx]));
      }
    }
  }
}

// ------------------------------------------------------------ scan step ----
// S_new[j] = S_old[j] + (j>=d ? S_old[j-d] @ V^T : 0), chunks 64x1024 bf16.
__global__ __launch_bounds__(256) void scan_step(
    const ushort_t* __restrict__ Sold, const ushort_t* __restrict__ V,
    ushort_t* __restrict__ Snew, int d) {
  __shared__ __align__(16) ushort_t AsF[4096];
  __shared__ __align__(16) ushort_t BsF[4096];
  const int p = blockIdx.x >> 3;
  const int n0 = (blockIdx.x & 7) * 128;
  const int tid = threadIdx.x;
  const int w = tid >> 6, l = tid & 63;
  const int quad = l >> 4, l15 = l & 15;
  const int wm = (w & 1) * 64, wn = (w >> 1) * 64;
  const int r0 = tid >> 2, chunk = tid & 3;
  f32x4 acc[4][4] = {};
  const int j0 = 2 * p, j1 = 2 * p + 1;
  const int s0 = (j0 >= d) ? j0 - d : j0;
  const int s1 = (j1 >= d) ? j1 - d : j1;
  const ushort_t* a0 = Sold + (size_t)s0 * 65536 + (size_t)r0 * 1024;
  const ushort_t* a1 = Sold + (size_t)s1 * 65536 + (size_t)r0 * 1024;
  for (int k0 = 0; k0 < 1024; k0 += 32) {
    __syncthreads();
    gload16(a0 + k0 + chunk * 8, &AsF[tid * 8]);
    gload16(a1 + k0 + chunk * 8, &AsF[2048 + tid * 8]);
    gload16(V + (size_t)(n0 + r0) * 1024 + k0 + chunk * 8,      &BsF[tid * 8]);
    gload16(V + (size_t)(n0 + r0 + 64) * 1024 + k0 + chunk * 8, &BsF[2048 + tid * 8]);
    __syncthreads();
    bf16x8 af[4], bfr[4];
#pragma unroll
    for (int i = 0; i < 4; ++i) af[i]  = *(const bf16x8*)&AsF[(wm + 16 * i + l15) * 32 + 8 * quad];
#pragma unroll
    for (int j = 0; j < 4; ++j) bfr[j] = *(const bf16x8*)&BsF[(wn + 16 * j + l15) * 32 + 8 * quad];
#pragma unroll
    for (int i = 0; i < 4; ++i)
#pragma unroll
      for (int j = 0; j < 4; ++j)
        acc[i][j] = __builtin_amdgcn_mfma_f32_16x16x32_bf16(af[i], bfr[j], acc[i][j], 0, 0, 0);
  }
#pragma unroll
  for (int i = 0; i < 4; ++i) {
#pragma unroll
    for (int j = 0; j < 4; ++j) {
      const int col = n0 + wn + 16 * j + l15;
#pragma unroll
      for (int r = 0; r < 4; ++r) {
        const int gr = wm + 16 * i + 4 * quad + r;
        const int c = 2 * p + (gr >> 6);
        const size_t idx = (size_t)c * 65536 + (size_t)(gr & 63) * 1024 + col;
        const float g = (c >= d) ? acc[i][j][r] : 0.0f;
        Snew[idx] = f2bf(g + bf2f(Sold[idx]));
      }
    }
  }
}

// ----------------------------------------------------------- correction ----
// ONE launch, grid (256, 8): j = blockIdx.y+1, sub-GEMM per j:
//   Harr[8c+j] += S[c] @ (W^j)^T   for all 64 chunks c (M=4096 per j).
// Covers j=1..8 -> writes ALL true h into slots 1..512 (slot 8c+8 == next
// chunk start; j=8 with W^8 reproduces the scan recurrence exactly).
__global__ __launch_bounds__(256) void correct_kernel(
    const ushort_t* __restrict__ S, ushort_t* __restrict__ Harr,
    const ushort_t* __restrict__ B1, const ushort_t* __restrict__ B2,
    const ushort_t* __restrict__ B3, const ushort_t* __restrict__ B4,
    const ushort_t* __restrict__ B5, const ushort_t* __restrict__ B6,
    const ushort_t* __restrict__ B7, const ushort_t* __restrict__ B8) {
  __shared__ __align__(16) ushort_t AsF[4096];
  __shared__ __align__(16) ushort_t BsF[4096];
  const int p = blockIdx.x >> 3;
  const int n0 = (blockIdx.x & 7) * 128;
  const int j = blockIdx.y + 1;
  const ushort_t* Wj;
  switch (j) {
    case 1: Wj = B1; break; case 2: Wj = B2; break;
    case 3: Wj = B3; break; case 4: Wj = B4; break;
    case 5: Wj = B5; break; case 6: Wj = B6; break;
    case 7: Wj = B7; break; default: Wj = B8; break;
  }
  ushort_t* XO = Harr + (size_t)j * 65536;   // p1 in, true h out (in place)
  const int tid = threadIdx.x;
  const int w = tid >> 6, l = tid & 63;
  const int quad = l >> 4, l15 = l & 15;
  const int wm = (w & 1) * 64, wn = (w >> 1) * 64;
  const int r0 = tid >> 2, chunk = tid & 3;
  f32x4 acc[4][4] = {};
  const ushort_t* a0 = S + (size_t)(2 * p) * 65536 + (size_t)r0 * 1024;
  const ushort_t* a1 = S + (size_t)(2 * p + 1) * 65536 + (size_t)r0 * 1024;
  for (int k0 = 0; k0 < 1024; k0 += 32) {
    __syncthreads();
    gload16(a0 + k0 + chunk * 8, &AsF[tid * 8]);
    gload16(a1 + k0 + chunk * 8, &AsF[2048 + tid * 8]);
    gload16(Wj + (size_t)(n0 + r0) * 1024 + k0 + chunk * 8,      &BsF[tid * 8]);
    gload16(Wj + (size_t)(n0 + r0 + 64) * 1024 + k0 + chunk * 8, &BsF[2048 + tid * 8]);
    __syncthreads();
    bf16x8 af[4], bfr[4];
#pragma unroll
    for (int i = 0; i < 4; ++i) af[i]  = *(const bf16x8*)&AsF[(wm + 16 * i + l15) * 32 + 8 * quad];
#pragma unroll
    for (int jj = 0; jj < 4; ++jj) bfr[jj] = *(const bf16x8*)&BsF[(wn + 16 * jj + l15) * 32 + 8 * quad];
#pragma unroll
    for (int i = 0; i < 4; ++i)
#pragma unroll
      for (int jj = 0; jj < 4; ++jj)
        acc[i][jj] = __builtin_amdgcn_mfma_f32_16x16x32_bf16(af[i], bfr[jj], acc[i][jj], 0, 0, 0);
  }
#pragma unroll
  for (int i = 0; i < 4; ++i) {
#pragma unroll
    for (int jj = 0; jj < 4; ++jj) {
      const int col = n0 + wn + 16 * jj + l15;
#pragma unroll
      for (int r = 0; r < 4; ++r) {
        const int gr = wm + 16 * i + 4 * quad + r;
        const int c = 2 * p + (gr >> 6);
        const size_t idx = (size_t)c * 524288 + (size_t)(gr & 63) * 1024 + col;
        XO[idx] = f2bf(acc[i][jj][r] + bf2f(XO[idx]));
      }
    }
  }
}

// ------------------------------------------------------------- copies ------
__global__ __launch_bounds__(256) void copy_strided(
    ushort_t* __restrict__ dst, size_t dStride,
    const ushort_t* __restrict__ src, size_t sStride) {
  const int c = blockIdx.x >> 5, part = blockIdx.x & 31;
  const size_t off = (size_t)part * 2048 + (size_t)threadIdx.x * 8;
  *(uint4*)(dst + (size_t)c * dStride + off) = *(const uint4*)(src + (size_t)c * sStride + off);
}

// -------------------------------------------------------- mask + softmax ---
__global__ __launch_bounds__(256) void softmax_kernel(
    float* __restrict__ out, const float* __restrict__ mask) {
  const int row = blockIdx.x;
  const int tid = threadIdx.x;
  const size_t base = (size_t)row * 512;
  __shared__ float sm[4], ss[4];
  const float v0 = out[base + tid] * mask[base + tid];
  const float v1 = out[base + tid + 256] * mask[base + tid + 256];
  float m = fmaxf(v0, v1);
#pragma unroll
  for (int off = 32; off; off >>= 1) m = fmaxf(m, __shfl_xor(m, off, 64));
  const int w = tid >> 6;
  if ((tid & 63) == 0) sm[w] = m;
  __syncthreads();
  m = fmaxf(fmaxf(sm[0], sm[1]), fmaxf(sm[2], sm[3]));
  float s = __expf(v0 - m) + __expf(v1 - m);
#pragma unroll
  for (int off = 32; off; off >>= 1) s += __shfl_xor(s, off, 64);
  if ((tid & 63) == 0) ss[w] = s;
  __syncthreads();
  s = ss[0] + ss[1] + ss[2] + ss[3];
  const float lg = logf(s);
  out[base + tid] = v0 - m - lg;
  out[base + tid + 256] = v1 - m - lg;
}

// ---------------------------------------------------------------------------
extern "C" void kernel_launch(void* const* d_in, const int* in_sizes, int n_in,
                              void* d_out, int out_size, void* d_ws, size_t ws_size,
                              hipStream_t stream) {
  const float* x     = (const float*)d_in[0];
  const float* mask  = (const float*)d_in[1];
  const float* W_i2h = (const float*)d_in[2];
  const float* b_i2h = (const float*)d_in[3];
  const float* W_i2o = (const float*)d_in[4];
  const float* b_i2o = (const float*)d_in[5];
  const float* W_o2o = (const float*)d_in[6];
  const float* b_o2o = (const float*)d_in[7];
  float* out = (float*)d_out;

  char* ws = (char*)d_ws;
  const size_t NEED = 207753216;
  if (ws_size < NEED) return;
  ushort_t* xB   = (ushort_t*)(ws + 0);            // [32768,512] bf16
  ushort_t* XhB  = (ushort_t*)(ws + 33554432);     // [512][64,1024] bf16
  ushort_t* Harr = (ushort_t*)(ws + 100663296);    // [513][64,1024] bf16
  char* outbRegion = ws + 167903232;               // 33,554,432 B
  ushort_t* OUTB = (ushort_t*)outbRegion;          // [32768,512] bf16 (late)
  // Scan-phase overlays (dead before OUTB is written):
  ushort_t* SA = (ushort_t*)(outbRegion + 0);          // [64][64,1024]
  ushort_t* SB = (ushort_t*)(outbRegion + 8388608);    // [64][64,1024]
  ushort_t* PB = (ushort_t*)(outbRegion + 16777216);   // 8 x [1024,1024]
  // Slots: 0:W^2 1:W^4 2:W^8 3:W^16(->W^3) 4:W^32(->W^5) 5:W^64(->W^6)
  //        6:W^128(->W^7) 7:W^256     (1048576 ushorts each)
  ushort_t* P2 = PB, *P4 = PB + 1048576, *P8 = PB + 2097152,
          * S3 = PB + 3145728, *S5 = PB + 4194304, *S6 = PB + 5242880,
          * S7 = PB + 6291456, *P256 = PB + 7340032;
  ushort_t* P16 = S3, *P32 = S5, *P64 = S6, *P128 = S7;  // pre-scan aliases
  ushort_t* Wihx = (ushort_t*)(ws + 201457664);
  ushort_t* Whh  = (ushort_t*)(ws + 202506240);
  ushort_t* Wiox = (ushort_t*)(ws + 204603392);
  ushort_t* Wioh = (ushort_t*)(ws + 205127680);
  ushort_t* Wo1  = (ushort_t*)(ws + 206176256);
  ushort_t* Wo2  = (ushort_t*)(ws + 206700544);

  hipLaunchKernelGGL(init_kernel, dim3(128), dim3(256), 0, stream, (uint32_t*)Harr);
  hipLaunchKernelGGL(pack_kernel, dim3(77824), dim3(256), 0, stream,
                     x, W_i2h, W_i2o, W_o2o, xB, Wihx, Whh, Wiox, Wioh, Wo1, Wo2);
  // Xh = xB @ Wihx^T + b_i2h  (M=32768, N=1024)
  hipLaunchKernelGGL(gemm_bt, dim3(2048), dim3(256), 0, stream,
                     xB, 512, Wihx, 512, (const ushort_t*)nullptr, 0,
                     (const ushort_t*)nullptr, 0, b_i2h, (float*)nullptr, XhB, 8);
  // Squaring chain W^2..W^256
  hipLaunchKernelGGL(gemm_bn, dim3(64), dim3(256), 0, stream, Whh, Whh, P2);
  hipLaunchKernelGGL(gemm_bn, dim3(64), dim3(256), 0, stream, P2, P2, P4);
  hipLaunchKernelGGL(gemm_bn, dim3(64), dim3(256), 0, stream, P4, P4, P8);
  hipLaunchKernelGGL(gemm_bn, dim3(64), dim3(256), 0, stream, P8, P8, P16);
  hipLaunchKernelGGL(gemm_bn, dim3(64), dim3(256), 0, stream, P16, P16, P32);
  hipLaunchKernelGGL(gemm_bn, dim3(64), dim3(256), 0, stream, P32, P32, P64);
  hipLaunchKernelGGL(gemm_bn, dim3(64), dim3(256), 0, stream, P64, P64, P128);
  hipLaunchKernelGGL(gemm_bn, dim3(64), dim3(256), 0, stream, P128, P128, P256);
  // Pass1 k=0: Harr[8c+1] = Xh[8c]
  hipLaunchKernelGGL(copy_strided, dim3(2048), dim3(256), 0, stream,
                     Harr + 65536, (size_t)524288, XhB, (size_t)524288);
  // Pass1 k=1..7
  for (int k = 1; k < 8; ++k)
    hipLaunchKernelGGL(rnn_step, dim3(256), dim3(256), 0, stream,
                       Harr + (size_t)k * 65536, (size_t)524288,
                       XhB + (size_t)k * 65536, Whh, Harr + (size_t)(k + 1) * 65536);
  // Scan init: SA[c] = Harr[8c]
  hipLaunchKernelGGL(copy_strided, dim3(2048), dim3(256), 0, stream,
                     SA, (size_t)65536, Harr, (size_t)524288);
  // Hillis-Steele (6 steps) -> final S in SA
  hipLaunchKernelGGL(scan_step, dim3(256), dim3(256), 0, stream, SA, P8,   SB, 1);
  hipLaunchKernelGGL(scan_step, dim3(256), dim3(256), 0, stream, SB, P16,  SA, 2);
  hipLaunchKernelGGL(scan_step, dim3(256), dim3(256), 0, stream, SA, P32,  SB, 4);
  hipLaunchKernelGGL(scan_step, dim3(256), dim3(256), 0, stream, SB, P64,  SA, 8);
  hipLaunchKernelGGL(scan_step, dim3(256), dim3(256), 0, stream, SA, P128, SB, 16);
  hipLaunchKernelGGL(scan_step, dim3(256), dim3(256), 0, stream, SB, P256, SA, 32);
  // Odd powers into dead scan-power slots: W^3, W^5, W^6, W^7
  hipLaunchKernelGGL(gemm_bn, dim3(64), dim3(256), 0, stream, Whh, P2, S3);
  hipLaunchKernelGGL(gemm_bn, dim3(64), dim3(256), 0, stream, Whh, P4, S5);
  hipLaunchKernelGGL(gemm_bn, dim3(64), dim3(256), 0, stream, P2,  P4, S6);
  hipLaunchKernelGGL(gemm_bn, dim3(64), dim3(256), 0, stream, S3,  P4, S7);
  // Correction: Harr[8c+j] += S_c @ (W^j)^T for j=1..8 (one parallel launch)
  hipLaunchKernelGGL(correct_kernel, dim3(256, 8), dim3(256), 0, stream,
                     SA, Harr, Whh, P2, S3, P4, S5, S6, S7, P8);
  // out = xB @ Wiox^T + h_prev @ Wioh^T + b_i2o  (N=512)
  hipLaunchKernelGGL(gemm_bt, dim3(1024), dim3(256), 0, stream,
                     xB, 512, Wiox, 512, Harr, 1024, Wioh, 1024,
                     b_i2o, (float*)nullptr, OUTB, 4);
  // oc = OUTB @ Wo1^T + h_new @ Wo2^T + b_o2o -> d_out fp32  (N=512)
  hipLaunchKernelGGL(gemm_bt, dim3(1024), dim3(256), 0, stream,
                     OUTB, 512, Wo1, 512, Harr + 65536, 1024, Wo2, 1024,
                     b_o2o, out, (ushort_t*)nullptr, 4);
  hipLaunchKernelGGL(softmax_kernel, dim3(32768), dim3(256), 0, stream, out, mask);
}